// Round 11
// baseline (186.409 us; speedup 1.0000x reference)
//
#include <hip/hip_runtime.h>
#include <hip/hip_bf16.h>
#include <math.h>

#define HW     192
#define PLANE  (HW*HW)        // 36864
#define CIN    64
#define COUT   64
#define NB     4
#define NPIX   (NB*PLANE)     // 147456
#define NBLK   (NPIX/16)      // 9216 deform blocks
#define H2     194
#define W2     200
#define WR     7
#define WC     21
#define NPOS   (WR*WC)        // 147

typedef __attribute__((ext_vector_type(8))) short bf16x8;
typedef __attribute__((ext_vector_type(4))) float f32x4;
typedef __attribute__((ext_vector_type(2))) float f32x2;

static __device__ __forceinline__ ushort f2bf(float f) {
    __hip_bfloat16 h = __float2bfloat16(f);
    return __builtin_bit_cast(ushort, h);
}
static __device__ __forceinline__ float bf2f(ushort u) {
    return __builtin_bit_cast(float, ((unsigned)u) << 16);
}
static __device__ __forceinline__ f32x2 up2(unsigned u) {   // (lo bf16, hi bf16)
    f32x2 r;
    r.x = __builtin_bit_cast(float, u << 16);
    r.y = __builtin_bit_cast(float, u & 0xffff0000u);
    return r;
}
static __device__ __forceinline__ unsigned pkbf(float a, float b) {
    __hip_bfloat162 b2 = __float22bfloat162_rn(make_float2(a, b));
    unsigned r;
    __builtin_memcpy(&r, &b2, sizeof(r));
    return r;
}

// ---------------- Kernel 1: transpose x -> channel-last padded bf16 + weights
// xt[b][y][col][c]: y 0..193, col 0..199, c 0..63; data at y,col in [1..192]
__global__ __launch_bounds__(256) void kpadprep(
    const float* __restrict__ x,
    const float* __restrict__ wc, const float* __restrict__ w_p,
    const float* __restrict__ w_m,
    ushort* __restrict__ xt, ushort* __restrict__ wbf, ushort* __restrict__ womf)
{
    int blk = blockIdx.x;
    int t   = threadIdx.x;
    if (blk < NB * H2) {                     // transpose path: one (b, y) row
        __shared__ ushort sT[W2 * 72];       // [col][c], col-stride 72 (28800 B)
        int b = blk / H2, y = blk % H2;
        bool yok = (y >= 1 && y <= HW);
        const float* xb = x + (size_t)b * CIN * PLANE + (size_t)(y - 1) * HW;
        // zero-fill cols {0, 193..199}
        {
            int zi  = t >> 5;
            int col = (zi == 0) ? 0 : 192 + zi;
            *(unsigned*)&sT[col * 72 + (t & 31) * 2] = 0;
        }
        // aligned float4 quads: cols 4q+1..4q+4 <- x[row][4q..4q+3]
#pragma unroll
        for (int it = 0; it < 6; ++it) {
            int idx = t + 256 * it;          // 0..1535 = 32 c-pairs x 48 quads
            int cp  = idx / 48;
            int q   = idx - cp * 48;
            int c   = cp * 2;
            float4 v0 = make_float4(0.f, 0.f, 0.f, 0.f), v1 = v0;
            if (yok) {
                v0 = *(const float4*)(xb + (size_t)c * PLANE + 4 * q);
                v1 = *(const float4*)(xb + (size_t)(c + 1) * PLANE + 4 * q);
            }
            float a0[4] = {v0.x, v0.y, v0.z, v0.w};
            float a1[4] = {v1.x, v1.y, v1.z, v1.w};
#pragma unroll
            for (int j = 0; j < 4; ++j)
                *(unsigned*)&sT[(4 * q + 1 + j) * 72 + c] =
                    (unsigned)f2bf(a0[j]) | ((unsigned)f2bf(a1[j]) << 16);
        }
        __syncthreads();
        uint4* dst = (uint4*)(xt + ((size_t)(b * H2 + y) * W2) * 64);
#pragma unroll
        for (int it = 0; it < 7; ++it) {
            int idx = t + 256 * it;          // 0..1599 = 200 cols x 8 octets
            if (idx < 1600) {
                int col = idx >> 3, g = idx & 7;
                dst[col * 8 + g] = *(uint4*)&sT[col * 72 + g * 8];
            }
        }
        return;
    }
    // weight prep path (27 blocks). k-order: k = n*64 + c
    int i = (blk - NB * H2) * 256 + t;       // 0..6911
    if (i < 4608) {
        int lane  = i & 63;
        int rc    = i >> 6;
        int chunk = rc % 18;
        int og    = rc / 18;
        int o  = og * 16 + (lane & 15);
        int k0 = chunk * 32 + (lane >> 4) * 8;
        ushort v[8];
#pragma unroll
        for (int j = 0; j < 8; ++j) {
            int k = k0 + j, c = k & 63, n = k >> 6;
            v[j] = f2bf(wc[o * 576 + c * 9 + n]);
        }
        ((uint4*)wbf)[i] = *(uint4*)v;
    } else if (i < 6912) {
        int ii    = i - 4608;
        int lane  = ii & 63;
        int rc    = ii >> 6;
        int chunk = rc % 18;
        int og    = rc / 18;
        int co = og * 16 + (lane & 15);
        int k0 = chunk * 32 + (lane >> 4) * 8;
        ushort v[8];
#pragma unroll
        for (int j = 0; j < 8; ++j) {
            int k = k0 + j, c = k & 63, n = k >> 6;
            float w = 0.f;
            if (co < 18)      w = w_p[(co * 64 + c) * 9 + n];
            else if (co < 27) w = w_m[((co - 18) * 64 + c) * 9 + n];
            v[j] = f2bf(w);
        }
        ((uint4*)womf)[ii] = *(uint4*)v;
    }
}

// ---------------- Kernel 2: offsets (MFMA) + sampling + GEMM + stat partials
// 256 threads = 4 waves, 16 consecutive pixels. Window channel-last in LDS,
// octet slot rotated by pos. LDS 40708 B -> 4 blocks/CU.
__global__ __launch_bounds__(256, 4) void kdeform(
    const ushort* __restrict__ xt,
    const ushort* __restrict__ wbf, const ushort* __restrict__ womf,
    const float* __restrict__ b_p, const float* __restrict__ b_m,
    ushort* __restrict__ outp,          // (B, 64, H, W) bf16
    float* __restrict__ partial)        // [128][NBLK]
{
    __shared__ __align__(16) char smem[40708];
    ushort* sWin = (ushort*)smem;                          // 18816 B (147*128)
    ushort* sXF  = (ushort*)(smem + 18816);                // 18432 B
    float (*sOMa)[17] = (float(*)[17])(smem + 18816);          // 2176 B overlay
    float (*sOMb)[17] = (float(*)[17])(smem + 18816 + 2176);   // 2176 B overlay
    float4 (*sG)[16] = (float4(*)[16])(smem + 37248);      // 2304 B
    uint (*sPos)[16] = (uint(*)[16])(smem + 39552);        // 576 B
    uint (*sOg)[16]  = (uint(*)[16])(smem + 40128);        // 576 B
    int* sFlag = (int*)(smem + 40704);

    int t    = threadIdx.x;
    int pix0 = blockIdx.x * 16;
    int b    = pix0 / PLANE;
    int rem  = pix0 - b * PLANE;
    int h    = rem / HW;
    int w0   = rem - h * HW;            // multiple of 16
    int rbase = min(max(h - 2, 0), H2 - WR);
    int wbase = min(max(w0 - 2, 0), W2 - WC - 4);   // keep right margin in-image
    if (t == 0) *sFlag = 0;

    const ushort* xtb = xt + (size_t)(b * H2) * W2 * 64;

    // ---- phase S: stage 7x21 window, channel-last, rotated octets ----
    {
        const uint4* gsrc = (const uint4*)(xtb + ((size_t)rbase * W2 + wbase) * 64);
#pragma unroll
        for (int it = 0; it < 5; ++it) {
            int idx = t + 256 * it;      // 0..1175 = 147 pos x 8 slots
            if (idx < NPOS * 8) {
                int pos = idx >> 3, s = idx & 7;
                int g   = (s - pos) & 7;
                int r   = (pos * 3121) >> 16;    // pos/21 for pos<1000
                int cc  = pos - r * WC;
                *(uint4*)&sWin[pos * 64 + s * 8] = gsrc[((r * W2 + cc) << 3) + g];
            }
        }
    }
    __syncthreads();

    // ---- phase B: offset+mask conv, all 4 waves (2 og x 2 k-halves) ----
    {
        int lane = t & 63;
        int wv   = t >> 6;
        int og   = wv & 1;
        int half = wv >> 1;             // chunks half*9 .. half*9+8
        int sub  = lane >> 4;
        int hr   = h - rbase;
        int wrp  = w0 - wbase + (lane & 15);
        f32x4 acc = {0.f, 0.f, 0.f, 0.f};
#pragma unroll
        for (int cc = 0; cc < 9; ++cc) {
            int chunk = half * 9 + cc;
            bf16x8 a = *(const bf16x8*)&womf[((og * 18 + chunk) * 64 + lane) * 8];
            int n  = chunk >> 1;
            int dy = n / 3, dx = n - dy * 3;
            int pos  = (hr + dy) * WC + wrp + dx;
            int slot = ((chunk & 1) * 4 + sub + pos) & 7;
            bf16x8 bb = *(const bf16x8*)&sWin[pos * 64 + slot * 8];
            acc = __builtin_amdgcn_mfma_f32_16x16x32_bf16(a, bb, acc, 0, 0, 0);
        }
        int col = lane & 15, row0 = sub * 4;
        float (*dst)[17] = half ? sOMb : sOMa;
#pragma unroll
        for (int r = 0; r < 4; ++r) dst[og * 16 + row0 + r][col] = acc[r];
    }
    __syncthreads();

    // ---- phase C: corner positions + bilinear*mask weights ----
    uint pkC = 0, ogC = 0; float4 gC = make_float4(0.f, 0.f, 0.f, 0.f);
    if (t < 144) {
        int pp = t & 15, n = t >> 4;
        float offy = sOMa[n][pp]      + sOMb[n][pp]      + b_p[n];
        float offx = sOMa[9 + n][pp]  + sOMb[9 + n][pp]  + b_p[9 + n];
        float mr   = sOMa[18 + n][pp] + sOMb[18 + n][pp] + b_m[n];
        float m = 1.f / (1.f + __expf(-mr));
        int dy = n / 3, dx = n - dy * 3;
        float py = (float)(h + dy) + offy;           // padded coords
        float px = (float)(w0 + pp + dx) + offx;
        float fy = floorf(py), fx = floorf(px);
        float qy0 = fminf(fmaxf(fy,       0.f), 193.f);
        float qy1 = fminf(fmaxf(fy + 1.f, 0.f), 193.f);
        float qx0 = fminf(fmaxf(fx,       0.f), 193.f);
        float qx1 = fminf(fmaxf(fx + 1.f, 0.f), 193.f);
        float pyc = fminf(fmaxf(py, 0.f), 193.f);
        float pxc = fminf(fmaxf(px, 0.f), 193.f);
        float ay = 1.f + qy0 - pyc, by = 1.f - (qy1 - pyc);
        float ax = 1.f + qx0 - pxc, bx = 1.f - (qx1 - pxc);
        int ry0 = (int)qy0, ry1 = (int)qy1;
        int cx0 = (int)qx0, cx1 = (int)qx1;
        int xs  = cx1 - cx0;                          // 0 or 1
        ogC = (uint)(ry0 | (ry1 << 8) | (cx0 << 16) | (xs << 24));
        int p00 = (ry0 - rbase) * WC + (cx0 - wbase);
        int p10 = (ry1 - rbase) * WC + (cx0 - wbase);
        pkC = (uint)((p00 & 255) | (((p00 + xs) & 255) << 8)
                   | ((p10 & 255) << 16) | (((p10 + xs) & 255) << 24));
        gC = make_float4(ay * ax * m, ay * bx * m, by * ax * m, by * bx * m);
        if (ry0 < rbase || ry1 > rbase + (WR - 1) ||
            cx0 < wbase || cx1 > wbase + (WC - 1))
            atomicOr(sFlag, 1);
    }
    __syncthreads();          // sOM overlays dead; sXF region reusable
    if (t < 144) {
        int pp = t & 15, n = t >> 4;
        sOg[n][pp]  = ogC;
        sPos[n][pp] = pkC;
        sG[n][pp]   = gC;
    }
    __syncthreads();

    // ---- phase D: bilinear sampling, 8 channels per b128, packed fp32 math --
    {
        int px  = t & 15, sub = t >> 4;
        int o8  = sub & 7;
        bool fb = (*sFlag != 0);
#pragma unroll
        for (int it = 0; it < 5; ++it) {
            int item = sub + 16 * it;            // (n, octet) work item
            if (item >= 72) break;
            int n = item >> 3;
            float4 G = sG[n][px];
            uint4 A0, A1, C0, C1;
            if (!fb) {
                uint pk = sPos[n][px];
                int p00 = pk & 255, p01 = (pk >> 8) & 255;
                int p10 = (pk >> 16) & 255, p11 = pk >> 24;
                A0 = *(const uint4*)&sWin[p00 * 64 + ((o8 + p00) & 7) * 8];
                A1 = *(const uint4*)&sWin[p01 * 64 + ((o8 + p01) & 7) * 8];
                C0 = *(const uint4*)&sWin[p10 * 64 + ((o8 + p10) & 7) * 8];
                C1 = *(const uint4*)&sWin[p11 * 64 + ((o8 + p11) & 7) * 8];
            } else {
                uint gp = sOg[n][px];
                int ry0 = gp & 255, ry1 = (gp >> 8) & 255;
                int cx0 = (gp >> 16) & 255, xs = gp >> 24;
                const ushort* g0 = xtb + (size_t)(ry0 * W2 + cx0) * 64 + o8 * 8;
                const ushort* g1 = xtb + (size_t)(ry1 * W2 + cx0) * 64 + o8 * 8;
                A0 = *(const uint4*)g0;
                A1 = *(const uint4*)(g0 + xs * 64);
                C0 = *(const uint4*)g1;
                C1 = *(const uint4*)(g1 + xs * 64);
            }
            unsigned ua0[4] = {A0.x, A0.y, A0.z, A0.w};
            unsigned ua1[4] = {A1.x, A1.y, A1.z, A1.w};
            unsigned uc0[4] = {C0.x, C0.y, C0.z, C0.w};
            unsigned uc1[4] = {C1.x, C1.y, C1.z, C1.w};
            unsigned pk4[4] __attribute__((aligned(16)));
#pragma unroll
            for (int q = 0; q < 4; ++q) {
                f32x2 v = G.x * up2(ua0[q]) + G.y * up2(ua1[q])
                        + G.z * up2(uc0[q]) + G.w * up2(uc1[q]);
                pk4[q] = pkbf(v.x, v.y);
            }
            int chunk = n * 2 + (o8 >> 2), s16 = o8 & 3;
            *(uint4*)&sXF[(chunk * 64 + s16 * 16 + (px ^ s16)) * 8] = *(uint4*)pk4;
        }
    }
    __syncthreads();

    // ---- phase E: main MFMA GEMM, store bf16; phase F: stats partials ----
    {
        int lane = t & 63, og = t >> 6;
        int sub = lane >> 4, pcol = lane & 15;
        f32x4 acc = {0.f, 0.f, 0.f, 0.f};
#pragma unroll
        for (int chunk = 0; chunk < 18; ++chunk) {
            bf16x8 a  = *(const bf16x8*)&wbf[((og * 18 + chunk) * 64 + lane) * 8];
            bf16x8 bb = *(const bf16x8*)&sXF[(chunk * 64 + sub * 16 + (pcol ^ sub)) * 8];
            acc = __builtin_amdgcn_mfma_f32_16x16x32_bf16(a, bb, acc, 0, 0, 0);
        }
        int row0 = sub * 4;
        ushort* ob = outp + ((size_t)(b * COUT + og * 16 + row0)) * PLANE + rem + pcol;
        ob[0]                 = f2bf(acc[0]);
        ob[(size_t)PLANE]     = f2bf(acc[1]);
        ob[2 * (size_t)PLANE] = f2bf(acc[2]);
        ob[3 * (size_t)PLANE] = f2bf(acc[3]);

        // phase F: reduce over the 16 pixel-columns of each sub-group
        float s[4], s2[4];
#pragma unroll
        for (int r = 0; r < 4; ++r) { s[r] = acc[r]; s2[r] = acc[r] * acc[r]; }
#pragma unroll
        for (int m = 1; m < 16; m <<= 1) {
#pragma unroll
            for (int r = 0; r < 4; ++r) {
                s[r]  += __shfl_xor(s[r],  m);
                s2[r] += __shfl_xor(s2[r], m);
            }
        }
        if (pcol == 0) {
#pragma unroll
            for (int r = 0; r < 4; ++r) {
                int ch = og * 16 + row0 + r;
                partial[(size_t)ch * NBLK + blockIdx.x]        = s[r];
                partial[(size_t)(64 + ch) * NBLK + blockIdx.x] = s2[r];
            }
        }
    }
}

// ---------------- Kernel 3: finalize BN stats -> per-channel (g, bt) --------
__global__ __launch_bounds__(256) void kfinal(
    const float* __restrict__ partial,
    const float* __restrict__ gamma, const float* __restrict__ beta,
    float* __restrict__ stats)
{
    int o = blockIdx.x;          // 0..63
    int t = threadIdx.x;
    float s = 0.f, s2 = 0.f;
    const float4* p1 = (const float4*)(partial + (size_t)o * NBLK);
    const float4* p2 = (const float4*)(partial + (size_t)(64 + o) * NBLK);
#pragma unroll
    for (int it = 0; it < 9; ++it) {             // 2304 float4 per array
        int i = t + 256 * it;
        float4 v1 = p1[i], v2 = p2[i];
        s  += v1.x + v1.y + v1.z + v1.w;
        s2 += v2.x + v2.y + v2.z + v2.w;
    }
    __shared__ float rs[256], rs2[256];
    rs[t] = s; rs2[t] = s2;
    __syncthreads();
    for (int st = 128; st > 0; st >>= 1) {
        if (t < st) { rs[t] += rs[t + st]; rs2[t] += rs2[t + st]; }
        __syncthreads();
    }
    if (t == 0) {
        float inv  = 1.f / (float)(NB * PLANE);
        float mean = rs[0] * inv;
        float var  = rs2[0] * inv - mean * mean;
        float rsq  = rsqrtf(var + 1e-5f);
        float g = gamma[o] * rsq;
        stats[o]      = g;
        stats[64 + o] = beta[o] - mean * g;
    }
}

// ---------------- Kernel 4: BN apply + ReLU + 2x2 maxpool -------------------
__global__ __launch_bounds__(256) void kbnpool(
    const ushort* __restrict__ outp, const float* __restrict__ stats,
    const float* __restrict__ gamma, const float* __restrict__ beta,
    float* __restrict__ out)
{
    int i = blockIdx.x * 256 + threadIdx.x;   // 0..2359295 exact
    int wo  = i % 96;
    int tmp = i / 96;
    int ho  = tmp % 96; tmp /= 96;
    int o   = tmp % 64;
    int b   = tmp / 64;
    float g  = stats[o];
    float bt = stats[64 + o];
    const ushort* pl = outp + ((size_t)(b * COUT + o)) * PLANE + (2 * ho) * HW + 2 * wo;
    unsigned u01 = *(const unsigned*)pl;
    unsigned u23 = *(const unsigned*)(pl + HW);
    float y00 = fmaxf(g * bf2f((ushort)(u01 & 0xffff)) + bt, 0.f);
    float y01 = fmaxf(g * bf2f((ushort)(u01 >> 16))    + bt, 0.f);
    float y10 = fmaxf(g * bf2f((ushort)(u23 & 0xffff)) + bt, 0.f);
    float y11 = fmaxf(g * bf2f((ushort)(u23 >> 16))    + bt, 0.f);
    out[i] = fmaxf(fmaxf(y00, y01), fmaxf(y10, y11));
}

// ---------------- launcher --------------------------------------------------
extern "C" void kernel_launch(void* const* d_in, const int* in_sizes, int n_in,
                              void* d_out, int out_size, void* d_ws, size_t ws_size,
                              hipStream_t stream)
{
    const float* x      = (const float*)d_in[0];
    const float* w_p    = (const float*)d_in[1];
    const float* b_p    = (const float*)d_in[2];
    const float* w_m    = (const float*)d_in[3];
    const float* b_m    = (const float*)d_in[4];
    const float* w_conv = (const float*)d_in[5];
    const float* gamma  = (const float*)d_in[6];
    const float* beta   = (const float*)d_in[7];
    float* out = (float*)d_out;

    char* ws = (char*)d_ws;
    ushort* xt      = (ushort*)ws;                    // 19,865,600 B
    ushort* outp    = (ushort*)(ws + 19865600);       // 18,874,368 B
    float*  partial = (float*)(ws + 38739968);        // 128*9216*4 = 4,718,592 B
    float*  stats   = (float*)(ws + 43458560);        // 512 B
    ushort* wbf     = (ushort*)(ws + 43459072);       // 73,728 B
    ushort* womf    = (ushort*)(ws + 43532800);       // 36,864 B (end ~43.6 MB)

    kpadprep<<<NB * H2 + 27, 256, 0, stream>>>(x, w_conv, w_p, w_m, xt, wbf, womf);
    kdeform<<<NBLK, 256, 0, stream>>>(xt, wbf, womf, b_p, b_m, outp, partial);
    kfinal<<<64, 256, 0, stream>>>(partial, gamma, beta, stats);
    kbnpool<<<(NB * COUT * 96 * 96) / 256, 256, 0, stream>>>(outp, stats, gamma, beta, out);
}

// Round 12
// 176.650 us; speedup vs baseline: 1.0552x; 1.0552x over previous
//
#include <hip/hip_runtime.h>
#include <hip/hip_bf16.h>
#include <math.h>

#define HW     192
#define PLANE  (HW*HW)        // 36864
#define CIN    64
#define COUT   64
#define NB     4
#define NPIX   (NB*PLANE)     // 147456
#define NBLK   (NPIX/16)      // 9216 deform blocks
#define H2     194
#define W2     200
#define WR     7
#define WC     21
#define NPOS   (WR*WC)        // 147

typedef __attribute__((ext_vector_type(8))) short bf16x8;
typedef __attribute__((ext_vector_type(4))) float f32x4;
typedef __attribute__((ext_vector_type(2))) float f32x2;

static __device__ __forceinline__ ushort f2bf(float f) {
    __hip_bfloat16 h = __float2bfloat16(f);
    return __builtin_bit_cast(ushort, h);
}
static __device__ __forceinline__ float bf2f(ushort u) {
    return __builtin_bit_cast(float, ((unsigned)u) << 16);
}
static __device__ __forceinline__ f32x2 up2(unsigned u) {   // (lo bf16, hi bf16)
    f32x2 r;
    r.x = __builtin_bit_cast(float, u << 16);
    r.y = __builtin_bit_cast(float, u & 0xffff0000u);
    return r;
}
static __device__ __forceinline__ unsigned pkbf(float a, float b) {
    __hip_bfloat162 b2 = __float22bfloat162_rn(make_float2(a, b));
    unsigned r;
    __builtin_memcpy(&r, &b2, sizeof(r));
    return r;
}

// ---------------- Kernel 1: transpose x -> channel-last padded bf16 + weights
// xt[b][y][col][c]: y 0..193, col 0..199, c 0..63; data at y,col in [1..192]
__global__ __launch_bounds__(256) void kpadprep(
    const float* __restrict__ x,
    const float* __restrict__ wc, const float* __restrict__ w_p,
    const float* __restrict__ w_m,
    ushort* __restrict__ xt, ushort* __restrict__ wbf, ushort* __restrict__ womf)
{
    int blk = blockIdx.x;
    int t   = threadIdx.x;
    if (blk < NB * H2) {                     // transpose path: one (b, y) row
        __shared__ ushort sT[W2 * 72];       // [col][c], col-stride 72 (28800 B)
        int b = blk / H2, y = blk % H2;
        bool yok = (y >= 1 && y <= HW);
        const float* xb = x + (size_t)b * CIN * PLANE + (size_t)(y - 1) * HW;
        // zero-fill cols {0, 193..199}
        {
            int zi  = t >> 5;
            int col = (zi == 0) ? 0 : 192 + zi;
            *(unsigned*)&sT[col * 72 + (t & 31) * 2] = 0;
        }
        // aligned float4 quads: cols 4q+1..4q+4 <- x[row][4q..4q+3]
#pragma unroll
        for (int it = 0; it < 6; ++it) {
            int idx = t + 256 * it;          // 0..1535 = 32 c-pairs x 48 quads
            int cp  = idx / 48;
            int q   = idx - cp * 48;
            int c   = cp * 2;
            float4 v0 = make_float4(0.f, 0.f, 0.f, 0.f), v1 = v0;
            if (yok) {
                v0 = *(const float4*)(xb + (size_t)c * PLANE + 4 * q);
                v1 = *(const float4*)(xb + (size_t)(c + 1) * PLANE + 4 * q);
            }
            float a0[4] = {v0.x, v0.y, v0.z, v0.w};
            float a1[4] = {v1.x, v1.y, v1.z, v1.w};
#pragma unroll
            for (int j = 0; j < 4; ++j)
                *(unsigned*)&sT[(4 * q + 1 + j) * 72 + c] =
                    (unsigned)f2bf(a0[j]) | ((unsigned)f2bf(a1[j]) << 16);
        }
        __syncthreads();
        uint4* dst = (uint4*)(xt + ((size_t)(b * H2 + y) * W2) * 64);
#pragma unroll
        for (int it = 0; it < 7; ++it) {
            int idx = t + 256 * it;          // 0..1599 = 200 cols x 8 octets
            if (idx < 1600) {
                int col = idx >> 3, g = idx & 7;
                dst[col * 8 + g] = *(uint4*)&sT[col * 72 + g * 8];
            }
        }
        return;
    }
    // weight prep path (27 blocks). k-order: k = n*64 + c
    int i = (blk - NB * H2) * 256 + t;       // 0..6911
    if (i < 4608) {
        int lane  = i & 63;
        int rc    = i >> 6;
        int chunk = rc % 18;
        int og    = rc / 18;
        int o  = og * 16 + (lane & 15);
        int k0 = chunk * 32 + (lane >> 4) * 8;
        ushort v[8];
#pragma unroll
        for (int j = 0; j < 8; ++j) {
            int k = k0 + j, c = k & 63, n = k >> 6;
            v[j] = f2bf(wc[o * 576 + c * 9 + n]);
        }
        ((uint4*)wbf)[i] = *(uint4*)v;
    } else if (i < 6912) {
        int ii    = i - 4608;
        int lane  = ii & 63;
        int rc    = ii >> 6;
        int chunk = rc % 18;
        int og    = rc / 18;
        int co = og * 16 + (lane & 15);
        int k0 = chunk * 32 + (lane >> 4) * 8;
        ushort v[8];
#pragma unroll
        for (int j = 0; j < 8; ++j) {
            int k = k0 + j, c = k & 63, n = k >> 6;
            float w = 0.f;
            if (co < 18)      w = w_p[(co * 64 + c) * 9 + n];
            else if (co < 27) w = w_m[((co - 18) * 64 + c) * 9 + n];
            v[j] = f2bf(w);
        }
        ((uint4*)womf)[ii] = *(uint4*)v;
    }
}

// ---------------- Kernel 2: offsets (MFMA) + sampling + main GEMM -----------
// 256 threads = 4 waves, 16 consecutive pixels. sXF OVERLAYS sWin (phase D
// buffers fragments in registers across a barrier). LDS 26628 B -> 6 blocks/CU.
__global__ __launch_bounds__(256, 6) void kdeform(
    const ushort* __restrict__ xt,
    const ushort* __restrict__ wbf, const ushort* __restrict__ womf,
    const float* __restrict__ b_p, const float* __restrict__ b_m,
    ushort* __restrict__ outp)          // (B, 64, H, W) bf16
{
    __shared__ __align__(16) char smem[26628];
    ushort* sWin = (ushort*)smem;                          // 18816 B (147*128)
    ushort* sXF  = (ushort*)smem;                          // overlay after D
    float (*sOMa)[17] = (float(*)[17])(smem + 18816);      // 2176 B
    float (*sOMb)[17] = (float(*)[17])(smem + 20992);      // 2176 B
    float4 (*sG)[16] = (float4(*)[16])(smem + 23168);      // 2304 B
    uint (*sPos)[16] = (uint(*)[16])(smem + 25472);        // 576 B
    uint (*sOg)[16]  = (uint(*)[16])(smem + 26048);        // 576 B
    int* sFlag = (int*)(smem + 26624);                     // 4 B

    int t    = threadIdx.x;
    int pix0 = blockIdx.x * 16;
    int b    = pix0 / PLANE;
    int rem  = pix0 - b * PLANE;
    int h    = rem / HW;
    int w0   = rem - h * HW;            // multiple of 16
    int rbase = min(max(h - 2, 0), H2 - WR);
    int wbase = min(max(w0 - 2, 0), W2 - WC - 4);   // keep right margin in-image
    if (t == 0) *sFlag = 0;

    const ushort* xtb = xt + (size_t)(b * H2) * W2 * 64;

    // ---- phase S: stage 7x21 window, channel-last, rotated octets ----
    {
        const uint4* gsrc = (const uint4*)(xtb + ((size_t)rbase * W2 + wbase) * 64);
#pragma unroll
        for (int it = 0; it < 5; ++it) {
            int idx = t + 256 * it;      // 0..1175 = 147 pos x 8 slots
            if (idx < NPOS * 8) {
                int pos = idx >> 3, s = idx & 7;
                int g   = (s - pos) & 7;
                int r   = (pos * 3121) >> 16;    // pos/21 for pos<1000
                int cc  = pos - r * WC;
                *(uint4*)&sWin[pos * 64 + s * 8] = gsrc[((r * W2 + cc) << 3) + g];
            }
        }
    }
    __syncthreads();

    // ---- phase B: offset+mask conv, all 4 waves (2 og x 2 k-halves) ----
    {
        int lane = t & 63;
        int wv   = t >> 6;
        int og   = wv & 1;
        int half = wv >> 1;             // chunks half*9 .. half*9+8
        int sub  = lane >> 4;
        int hr   = h - rbase;
        int wrp  = w0 - wbase + (lane & 15);
        f32x4 acc = {0.f, 0.f, 0.f, 0.f};
#pragma unroll
        for (int cc = 0; cc < 9; ++cc) {
            int chunk = half * 9 + cc;
            bf16x8 a = *(const bf16x8*)&womf[((og * 18 + chunk) * 64 + lane) * 8];
            int n  = chunk >> 1;
            int dy = n / 3, dx = n - dy * 3;
            int pos  = (hr + dy) * WC + wrp + dx;
            int slot = ((chunk & 1) * 4 + sub + pos) & 7;
            bf16x8 bb = *(const bf16x8*)&sWin[pos * 64 + slot * 8];
            acc = __builtin_amdgcn_mfma_f32_16x16x32_bf16(a, bb, acc, 0, 0, 0);
        }
        int col = lane & 15, row0 = sub * 4;
        float (*dst)[17] = half ? sOMb : sOMa;
#pragma unroll
        for (int r = 0; r < 4; ++r) dst[og * 16 + row0 + r][col] = acc[r];
    }
    __syncthreads();

    // ---- phase C: corner positions + bilinear*mask weights ----
    if (t < 144) {
        int pp = t & 15, n = t >> 4;
        float offy = sOMa[n][pp]      + sOMb[n][pp]      + b_p[n];
        float offx = sOMa[9 + n][pp]  + sOMb[9 + n][pp]  + b_p[9 + n];
        float mr   = sOMa[18 + n][pp] + sOMb[18 + n][pp] + b_m[n];
        float m = 1.f / (1.f + __expf(-mr));
        int dy = n / 3, dx = n - dy * 3;
        float py = (float)(h + dy) + offy;           // padded coords
        float px = (float)(w0 + pp + dx) + offx;
        float fy = floorf(py), fx = floorf(px);
        float qy0 = fminf(fmaxf(fy,       0.f), 193.f);
        float qy1 = fminf(fmaxf(fy + 1.f, 0.f), 193.f);
        float qx0 = fminf(fmaxf(fx,       0.f), 193.f);
        float qx1 = fminf(fmaxf(fx + 1.f, 0.f), 193.f);
        float pyc = fminf(fmaxf(py, 0.f), 193.f);
        float pxc = fminf(fmaxf(px, 0.f), 193.f);
        float ay = 1.f + qy0 - pyc, by = 1.f - (qy1 - pyc);
        float ax = 1.f + qx0 - pxc, bx = 1.f - (qx1 - pxc);
        int ry0 = (int)qy0, ry1 = (int)qy1;
        int cx0 = (int)qx0, cx1 = (int)qx1;
        int xs  = cx1 - cx0;                          // 0 or 1
        sOg[n][pp] = (uint)(ry0 | (ry1 << 8) | (cx0 << 16) | (xs << 24));
        int p00 = (ry0 - rbase) * WC + (cx0 - wbase);
        int p10 = (ry1 - rbase) * WC + (cx0 - wbase);
        sPos[n][pp] = (uint)((p00 & 255) | (((p00 + xs) & 255) << 8)
                           | ((p10 & 255) << 16) | (((p10 + xs) & 255) << 24));
        sG[n][pp] = make_float4(ay * ax * m, ay * bx * m, by * ax * m, by * bx * m);
        if (ry0 < rbase || ry1 > rbase + (WR - 1) ||
            cx0 < wbase || cx1 > wbase + (WC - 1))
            atomicOr(sFlag, 1);
    }
    __syncthreads();

    // ---- phase D: bilinear sampling into REGISTERS (window still live) ----
    unsigned pk4s[5][4];
    {
        int px  = t & 15, sub = t >> 4;
        int o8  = sub & 7;
        bool fb = (*sFlag != 0);
#pragma unroll
        for (int it = 0; it < 5; ++it) {
            int item = sub + 16 * it;            // (n, octet) work item
            if (item < 72) {
                int n = item >> 3;
                float4 G = sG[n][px];
                uint4 A0, A1, C0, C1;
                if (!fb) {
                    uint pk = sPos[n][px];
                    int p00 = pk & 255, p01 = (pk >> 8) & 255;
                    int p10 = (pk >> 16) & 255, p11 = pk >> 24;
                    A0 = *(const uint4*)&sWin[p00 * 64 + ((o8 + p00) & 7) * 8];
                    A1 = *(const uint4*)&sWin[p01 * 64 + ((o8 + p01) & 7) * 8];
                    C0 = *(const uint4*)&sWin[p10 * 64 + ((o8 + p10) & 7) * 8];
                    C1 = *(const uint4*)&sWin[p11 * 64 + ((o8 + p11) & 7) * 8];
                } else {
                    uint gp = sOg[n][px];
                    int ry0 = gp & 255, ry1 = (gp >> 8) & 255;
                    int cx0 = (gp >> 16) & 255, xs = gp >> 24;
                    const ushort* g0 = xtb + (size_t)(ry0 * W2 + cx0) * 64 + o8 * 8;
                    const ushort* g1 = xtb + (size_t)(ry1 * W2 + cx0) * 64 + o8 * 8;
                    A0 = *(const uint4*)g0;
                    A1 = *(const uint4*)(g0 + xs * 64);
                    C0 = *(const uint4*)g1;
                    C1 = *(const uint4*)(g1 + xs * 64);
                }
                unsigned ua0[4] = {A0.x, A0.y, A0.z, A0.w};
                unsigned ua1[4] = {A1.x, A1.y, A1.z, A1.w};
                unsigned uc0[4] = {C0.x, C0.y, C0.z, C0.w};
                unsigned uc1[4] = {C1.x, C1.y, C1.z, C1.w};
#pragma unroll
                for (int q = 0; q < 4; ++q) {
                    f32x2 v = G.x * up2(ua0[q]) + G.y * up2(ua1[q])
                            + G.z * up2(uc0[q]) + G.w * up2(uc1[q]);
                    pk4s[it][q] = pkbf(v.x, v.y);
                }
            }
        }
    }
    __syncthreads();          // all window reads done; sWin dead -> sXF overlay

    // ---- phase D2: write fragments to sXF (overlaid on sWin) ----
    {
        int px  = t & 15, sub = t >> 4;
        int o8  = sub & 7;
#pragma unroll
        for (int it = 0; it < 5; ++it) {
            int item = sub + 16 * it;
            if (item < 72) {
                int n = item >> 3;
                int chunk = n * 2 + (o8 >> 2), s16 = o8 & 3;
                *(uint4*)&sXF[(chunk * 64 + s16 * 16 + (px ^ s16)) * 8] =
                    *(uint4*)pk4s[it];
            }
        }
    }
    __syncthreads();

    // ---- phase E: main MFMA GEMM, store bf16 ----
    {
        int lane = t & 63, og = t >> 6;
        int sub = lane >> 4, pcol = lane & 15;
        f32x4 acc = {0.f, 0.f, 0.f, 0.f};
#pragma unroll
        for (int chunk = 0; chunk < 18; ++chunk) {
            bf16x8 a  = *(const bf16x8*)&wbf[((og * 18 + chunk) * 64 + lane) * 8];
            bf16x8 bb = *(const bf16x8*)&sXF[(chunk * 64 + sub * 16 + (pcol ^ sub)) * 8];
            acc = __builtin_amdgcn_mfma_f32_16x16x32_bf16(a, bb, acc, 0, 0, 0);
        }
        int row0 = sub * 4;
        ushort* ob = outp + ((size_t)(b * COUT + og * 16 + row0)) * PLANE + rem + pcol;
        ob[0]                 = f2bf(acc[0]);
        ob[(size_t)PLANE]     = f2bf(acc[1]);
        ob[2 * (size_t)PLANE] = f2bf(acc[2]);
        ob[3 * (size_t)PLANE] = f2bf(acc[3]);
    }
}

// ---------------- Kernel 3: per-(channel,slice) partial stats, no atomics ---
__global__ __launch_bounds__(256) void kstats(
    const ushort* __restrict__ outp, float* __restrict__ partial)
{
    int o  = blockIdx.x >> 3;
    int sl = blockIdx.x & 7;
    int t  = threadIdx.x;
    float s = 0.f, s2 = 0.f;
    for (int b = 0; b < NB; ++b) {
        const uint4* pl = (const uint4*)(outp + ((size_t)(b * COUT + o)) * PLANE
                                         + sl * (PLANE / 8));
        for (int i = t; i < PLANE / 64; i += 256) {   // 576 uint4 per slice
            uint4 v = pl[i];
            unsigned ua[4] = {v.x, v.y, v.z, v.w};
#pragma unroll
            for (int j = 0; j < 4; ++j) {
                float lo = __builtin_bit_cast(float, ua[j] << 16);
                float hi = __builtin_bit_cast(float, ua[j] & 0xffff0000u);
                s  += lo + hi;
                s2 += lo * lo + hi * hi;
            }
        }
    }
    __shared__ float rs[256], rs2[256];
    rs[t] = s; rs2[t] = s2;
    __syncthreads();
    for (int st = 128; st > 0; st >>= 1) {
        if (t < st) { rs[t] += rs[t + st]; rs2[t] += rs2[t + st]; }
        __syncthreads();
    }
    if (t == 0) {
        partial[o * 8 + sl]       = rs[0];
        partial[512 + o * 8 + sl] = rs2[0];
    }
}

// ---------------- Kernel 4: BN finalize + ReLU + 2x2 maxpool ----------------
__global__ __launch_bounds__(256) void kbnpool(
    const ushort* __restrict__ outp, const float* __restrict__ partial,
    const float* __restrict__ gamma, const float* __restrict__ beta,
    float* __restrict__ out)
{
    int i = blockIdx.x * 256 + threadIdx.x;   // 0..2359295 exact
    int wo  = i % 96;
    int tmp = i / 96;
    int ho  = tmp % 96; tmp /= 96;
    int o   = tmp % 64;
    int b   = tmp / 64;
    float s = 0.f, s2 = 0.f;
#pragma unroll
    for (int sl = 0; sl < 8; ++sl) {
        s  += partial[o * 8 + sl];
        s2 += partial[512 + o * 8 + sl];
    }
    float inv  = 1.f / (float)(NB * PLANE);
    float mean = s * inv;
    float var  = s2 * inv - mean * mean;
    float rsq  = rsqrtf(var + 1e-5f);
    float g  = gamma[o] * rsq;
    float bt = beta[o] - mean * g;
    const ushort* pl = outp + ((size_t)(b * COUT + o)) * PLANE + (2 * ho) * HW + 2 * wo;
    unsigned u01 = *(const unsigned*)pl;
    unsigned u23 = *(const unsigned*)(pl + HW);
    float y00 = fmaxf(g * bf2f((ushort)(u01 & 0xffff)) + bt, 0.f);
    float y01 = fmaxf(g * bf2f((ushort)(u01 >> 16))    + bt, 0.f);
    float y10 = fmaxf(g * bf2f((ushort)(u23 & 0xffff)) + bt, 0.f);
    float y11 = fmaxf(g * bf2f((ushort)(u23 >> 16))    + bt, 0.f);
    out[i] = fmaxf(fmaxf(y00, y01), fmaxf(y10, y11));
}

// ---------------- launcher --------------------------------------------------
extern "C" void kernel_launch(void* const* d_in, const int* in_sizes, int n_in,
                              void* d_out, int out_size, void* d_ws, size_t ws_size,
                              hipStream_t stream)
{
    const float* x      = (const float*)d_in[0];
    const float* w_p    = (const float*)d_in[1];
    const float* b_p    = (const float*)d_in[2];
    const float* w_m    = (const float*)d_in[3];
    const float* b_m    = (const float*)d_in[4];
    const float* w_conv = (const float*)d_in[5];
    const float* gamma  = (const float*)d_in[6];
    const float* beta   = (const float*)d_in[7];
    float* out = (float*)d_out;

    char* ws = (char*)d_ws;
    ushort* xt      = (ushort*)ws;                    // 19,865,600 B
    ushort* outp    = (ushort*)(ws + 19865600);       // 18,874,368 B
    float*  partial = (float*)(ws + 38739968);        // 4096 B
    ushort* wbf     = (ushort*)(ws + 38744064);       // 73,728 B
    ushort* womf    = (ushort*)(ws + 38817792);       // 36,864 B

    kpadprep<<<NB * H2 + 27, 256, 0, stream>>>(x, w_conv, w_p, w_m, xt, wbf, womf);
    kdeform<<<NBLK, 256, 0, stream>>>(xt, wbf, womf, b_p, b_m, outp);
    kstats<<<512, 256, 0, stream>>>(outp, partial);
    kbnpool<<<(NB * COUT * 96 * 96) / 256, 256, 0, stream>>>(outp, partial, gamma, beta, out);
}

// Round 13
// 168.359 us; speedup vs baseline: 1.1072x; 1.0492x over previous
//
#include <hip/hip_runtime.h>
#include <hip/hip_bf16.h>
#include <math.h>

#define HW     192
#define PLANE  (HW*HW)        // 36864
#define CIN    64
#define COUT   64
#define NB     4
#define NPIX   (NB*PLANE)     // 147456
#define NBLK   (NPIX/16)      // 9216 deform blocks
#define H2     194
#define W2     200
#define WR     7
#define WC     21
#define NPOS   (WR*WC)        // 147

typedef __attribute__((ext_vector_type(8))) _Float16 f16x8;
typedef __attribute__((ext_vector_type(2))) _Float16 f16x2;
typedef __attribute__((ext_vector_type(4))) float f32x4;

static __device__ __forceinline__ ushort f2h(float f) {
    return __builtin_bit_cast(ushort, (_Float16)f);
}
static __device__ __forceinline__ float h2f(ushort u) {
    return (float)__builtin_bit_cast(_Float16, u);
}
static __device__ __forceinline__ f16x2 h2(unsigned u) {
    return __builtin_bit_cast(f16x2, u);
}

// ---------------- Kernel 1: transpose x -> channel-last padded f16 + weights
// xt[b][y][col][c]: y 0..193, col 0..199, c 0..63; data at y,col in [1..192]
__global__ __launch_bounds__(256) void kpadprep(
    const float* __restrict__ x,
    const float* __restrict__ wc, const float* __restrict__ w_p,
    const float* __restrict__ w_m,
    ushort* __restrict__ xt, ushort* __restrict__ wbf, ushort* __restrict__ womf)
{
    int blk = blockIdx.x;
    int t   = threadIdx.x;
    if (blk < NB * H2) {                     // transpose path: one (b, y) row
        __shared__ ushort sT[W2 * 72];       // [col][c], col-stride 72 (28800 B)
        int b = blk / H2, y = blk % H2;
        bool yok = (y >= 1 && y <= HW);
        const float* xb = x + (size_t)b * CIN * PLANE + (size_t)(y - 1) * HW;
        // zero-fill cols {0, 193..199}
        {
            int zi  = t >> 5;
            int col = (zi == 0) ? 0 : 192 + zi;
            *(unsigned*)&sT[col * 72 + (t & 31) * 2] = 0;
        }
        // aligned float4 quads: cols 4q+1..4q+4 <- x[row][4q..4q+3]
#pragma unroll
        for (int it = 0; it < 6; ++it) {
            int idx = t + 256 * it;          // 0..1535 = 32 c-pairs x 48 quads
            int cp  = idx / 48;
            int q   = idx - cp * 48;
            int c   = cp * 2;
            float4 v0 = make_float4(0.f, 0.f, 0.f, 0.f), v1 = v0;
            if (yok) {
                v0 = *(const float4*)(xb + (size_t)c * PLANE + 4 * q);
                v1 = *(const float4*)(xb + (size_t)(c + 1) * PLANE + 4 * q);
            }
            float a0[4] = {v0.x, v0.y, v0.z, v0.w};
            float a1[4] = {v1.x, v1.y, v1.z, v1.w};
#pragma unroll
            for (int j = 0; j < 4; ++j)
                *(unsigned*)&sT[(4 * q + 1 + j) * 72 + c] =
                    (unsigned)f2h(a0[j]) | ((unsigned)f2h(a1[j]) << 16);
        }
        __syncthreads();
        uint4* dst = (uint4*)(xt + ((size_t)(b * H2 + y) * W2) * 64);
#pragma unroll
        for (int it = 0; it < 7; ++it) {
            int idx = t + 256 * it;          // 0..1599 = 200 cols x 8 octets
            if (idx < 1600) {
                int col = idx >> 3, g = idx & 7;
                dst[col * 8 + g] = *(uint4*)&sT[col * 72 + g * 8];
            }
        }
        return;
    }
    // weight prep path (27 blocks). k-order: k = n*64 + c
    int i = (blk - NB * H2) * 256 + t;       // 0..6911
    if (i < 4608) {
        int lane  = i & 63;
        int rc    = i >> 6;
        int chunk = rc % 18;
        int og    = rc / 18;
        int o  = og * 16 + (lane & 15);
        int k0 = chunk * 32 + (lane >> 4) * 8;
        ushort v[8];
#pragma unroll
        for (int j = 0; j < 8; ++j) {
            int k = k0 + j, c = k & 63, n = k >> 6;
            v[j] = f2h(wc[o * 576 + c * 9 + n]);
        }
        ((uint4*)wbf)[i] = *(uint4*)v;
    } else if (i < 6912) {
        int ii    = i - 4608;
        int lane  = ii & 63;
        int rc    = ii >> 6;
        int chunk = rc % 18;
        int og    = rc / 18;
        int co = og * 16 + (lane & 15);
        int k0 = chunk * 32 + (lane >> 4) * 8;
        ushort v[8];
#pragma unroll
        for (int j = 0; j < 8; ++j) {
            int k = k0 + j, c = k & 63, n = k >> 6;
            float w = 0.f;
            if (co < 18)      w = w_p[(co * 64 + c) * 9 + n];
            else if (co < 27) w = w_m[((co - 18) * 64 + c) * 9 + n];
            v[j] = f2h(w);
        }
        ((uint4*)womf)[ii] = *(uint4*)v;
    }
}

// ---------------- Kernel 2: offsets (MFMA) + sampling + main GEMM -----------
// 256 threads = 4 waves, 16 consecutive pixels. All-f16 data path:
// window/G/x_s f16 -> packed v_pk_fma_f16 bilinear combine (no unpack/cvt),
// mfma f16. sXF overlays sWin. LDS 26628 B -> 6 blocks/CU.
__global__ __launch_bounds__(256, 6) void kdeform(
    const ushort* __restrict__ xt,
    const ushort* __restrict__ wbf, const ushort* __restrict__ womf,
    const float* __restrict__ b_p, const float* __restrict__ b_m,
    ushort* __restrict__ outp)          // (B, 64, H, W) f16
{
    __shared__ __align__(16) char smem[26628];
    ushort* sWin = (ushort*)smem;                          // 18816 B (147*128)
    ushort* sXF  = (ushort*)smem;                          // overlay after D
    float (*sOMa)[17] = (float(*)[17])(smem + 18816);      // 2176 B
    float (*sOMb)[17] = (float(*)[17])(smem + 20992);      // 2176 B
    uint4 (*sG)[16]  = (uint4(*)[16])(smem + 23168);       // 2304 B (4 f16-pairs)
    uint (*sPos)[16] = (uint(*)[16])(smem + 25472);        // 576 B
    uint (*sOg)[16]  = (uint(*)[16])(smem + 26048);        // 576 B
    int* sFlag = (int*)(smem + 26624);                     // 4 B

    int t    = threadIdx.x;
    int pix0 = blockIdx.x * 16;
    int b    = pix0 / PLANE;
    int rem  = pix0 - b * PLANE;
    int h    = rem / HW;
    int w0   = rem - h * HW;            // multiple of 16
    int rbase = min(max(h - 2, 0), H2 - WR);
    int wbase = min(max(w0 - 2, 0), W2 - WC - 4);   // keep right margin in-image
    if (t == 0) *sFlag = 0;

    const ushort* xtb = xt + (size_t)(b * H2) * W2 * 64;

    // ---- phase S: stage 7x21 window, channel-last, rotated octets ----
    {
        const uint4* gsrc = (const uint4*)(xtb + ((size_t)rbase * W2 + wbase) * 64);
#pragma unroll
        for (int it = 0; it < 5; ++it) {
            int idx = t + 256 * it;      // 0..1175 = 147 pos x 8 slots
            if (idx < NPOS * 8) {
                int pos = idx >> 3, s = idx & 7;
                int g   = (s - pos) & 7;
                int r   = (pos * 3121) >> 16;    // pos/21 for pos<1000
                int cc  = pos - r * WC;
                *(uint4*)&sWin[pos * 64 + s * 8] = gsrc[((r * W2 + cc) << 3) + g];
            }
        }
    }
    __syncthreads();

    // ---- phase B: offset+mask conv, all 4 waves (2 og x 2 k-halves) ----
    {
        int lane = t & 63;
        int wv   = t >> 6;
        int og   = wv & 1;
        int half = wv >> 1;             // chunks half*9 .. half*9+8
        int sub  = lane >> 4;
        int hr   = h - rbase;
        int wrp  = w0 - wbase + (lane & 15);
        f32x4 acc = {0.f, 0.f, 0.f, 0.f};
#pragma unroll
        for (int cc = 0; cc < 9; ++cc) {
            int chunk = half * 9 + cc;
            f16x8 a = *(const f16x8*)&womf[((og * 18 + chunk) * 64 + lane) * 8];
            int n  = chunk >> 1;
            int dy = n / 3, dx = n - dy * 3;
            int pos  = (hr + dy) * WC + wrp + dx;
            int slot = ((chunk & 1) * 4 + sub + pos) & 7;
            f16x8 bb = *(const f16x8*)&sWin[pos * 64 + slot * 8];
            acc = __builtin_amdgcn_mfma_f32_16x16x32_f16(a, bb, acc, 0, 0, 0);
        }
        int col = lane & 15, row0 = sub * 4;
        float (*dst)[17] = half ? sOMb : sOMa;
#pragma unroll
        for (int r = 0; r < 4; ++r) dst[og * 16 + row0 + r][col] = acc[r];
    }
    __syncthreads();

    // ---- phase C: corner positions + bilinear*mask weights (f16 pairs) ----
    if (t < 144) {
        int pp = t & 15, n = t >> 4;
        float offy = sOMa[n][pp]      + sOMb[n][pp]      + b_p[n];
        float offx = sOMa[9 + n][pp]  + sOMb[9 + n][pp]  + b_p[9 + n];
        float mr   = sOMa[18 + n][pp] + sOMb[18 + n][pp] + b_m[n];
        float m = 1.f / (1.f + __expf(-mr));
        int dy = n / 3, dx = n - dy * 3;
        float py = (float)(h + dy) + offy;           // padded coords
        float px = (float)(w0 + pp + dx) + offx;
        float fy = floorf(py), fx = floorf(px);
        float qy0 = fminf(fmaxf(fy,       0.f), 193.f);
        float qy1 = fminf(fmaxf(fy + 1.f, 0.f), 193.f);
        float qx0 = fminf(fmaxf(fx,       0.f), 193.f);
        float qx1 = fminf(fmaxf(fx + 1.f, 0.f), 193.f);
        float pyc = fminf(fmaxf(py, 0.f), 193.f);
        float pxc = fminf(fmaxf(px, 0.f), 193.f);
        float ay = 1.f + qy0 - pyc, by = 1.f - (qy1 - pyc);
        float ax = 1.f + qx0 - pxc, bx = 1.f - (qx1 - pxc);
        int ry0 = (int)qy0, ry1 = (int)qy1;
        int cx0 = (int)qx0, cx1 = (int)qx1;
        int xs  = cx1 - cx0;                          // 0 or 1
        sOg[n][pp] = (uint)(ry0 | (ry1 << 8) | (cx0 << 16) | (xs << 24));
        int p00 = (ry0 - rbase) * WC + (cx0 - wbase);
        int p10 = (ry1 - rbase) * WC + (cx0 - wbase);
        sPos[n][pp] = (uint)((p00 & 255) | (((p00 + xs) & 255) << 8)
                           | ((p10 & 255) << 16) | (((p10 + xs) & 255) << 24));
        uint g0 = f2h(ay * ax * m), g1 = f2h(ay * bx * m);
        uint g2 = f2h(by * ax * m), g3 = f2h(by * bx * m);
        sG[n][pp] = make_uint4(g0 | (g0 << 16), g1 | (g1 << 16),
                               g2 | (g2 << 16), g3 | (g3 << 16));
        if (ry0 < rbase || ry1 > rbase + (WR - 1) ||
            cx0 < wbase || cx1 > wbase + (WC - 1))
            atomicOr(sFlag, 1);
    }
    __syncthreads();

    // ---- phase D: bilinear sampling into REGISTERS, packed f16 fma ----
    unsigned pk4s[5][4];
    {
        int px  = t & 15, sub = t >> 4;
        int o8  = sub & 7;
        bool fb = (*sFlag != 0);
#pragma unroll
        for (int it = 0; it < 5; ++it) {
            int item = sub + 16 * it;            // (n, octet) work item
            if (item < 72) {
                int n = item >> 3;
                uint4 Gp = sG[n][px];
                f16x2 g0 = h2(Gp.x), g1 = h2(Gp.y), g2 = h2(Gp.z), g3 = h2(Gp.w);
                uint4 A0, A1, C0, C1;
                if (!fb) {
                    uint pk = sPos[n][px];
                    int p00 = pk & 255, p01 = (pk >> 8) & 255;
                    int p10 = (pk >> 16) & 255, p11 = pk >> 24;
                    A0 = *(const uint4*)&sWin[p00 * 64 + ((o8 + p00) & 7) * 8];
                    A1 = *(const uint4*)&sWin[p01 * 64 + ((o8 + p01) & 7) * 8];
                    C0 = *(const uint4*)&sWin[p10 * 64 + ((o8 + p10) & 7) * 8];
                    C1 = *(const uint4*)&sWin[p11 * 64 + ((o8 + p11) & 7) * 8];
                } else {
                    uint gp = sOg[n][px];
                    int ry0 = gp & 255, ry1 = (gp >> 8) & 255;
                    int cx0 = (gp >> 16) & 255, xs = gp >> 24;
                    const ushort* g0p = xtb + (size_t)(ry0 * W2 + cx0) * 64 + o8 * 8;
                    const ushort* g1p = xtb + (size_t)(ry1 * W2 + cx0) * 64 + o8 * 8;
                    A0 = *(const uint4*)g0p;
                    A1 = *(const uint4*)(g0p + xs * 64);
                    C0 = *(const uint4*)g1p;
                    C1 = *(const uint4*)(g1p + xs * 64);
                }
                unsigned ua0[4] = {A0.x, A0.y, A0.z, A0.w};
                unsigned ua1[4] = {A1.x, A1.y, A1.z, A1.w};
                unsigned uc0[4] = {C0.x, C0.y, C0.z, C0.w};
                unsigned uc1[4] = {C1.x, C1.y, C1.z, C1.w};
#pragma unroll
                for (int q = 0; q < 4; ++q) {
                    f16x2 v = g0 * h2(ua0[q]) + g1 * h2(ua1[q])
                            + g2 * h2(uc0[q]) + g3 * h2(uc1[q]);
                    pk4s[it][q] = __builtin_bit_cast(unsigned, v);
                }
            }
        }
    }
    __syncthreads();          // all window reads done; sWin dead -> sXF overlay

    // ---- phase D2: write fragments to sXF (overlaid on sWin) ----
    {
        int px  = t & 15, sub = t >> 4;
        int o8  = sub & 7;
#pragma unroll
        for (int it = 0; it < 5; ++it) {
            int item = sub + 16 * it;
            if (item < 72) {
                int n = item >> 3;
                int chunk = n * 2 + (o8 >> 2), s16 = o8 & 3;
                *(uint4*)&sXF[(chunk * 64 + s16 * 16 + (px ^ s16)) * 8] =
                    *(uint4*)pk4s[it];
            }
        }
    }
    __syncthreads();

    // ---- phase E: main MFMA GEMM (f16), store f16 ----
    {
        int lane = t & 63, og = t >> 6;
        int sub = lane >> 4, pcol = lane & 15;
        f32x4 acc = {0.f, 0.f, 0.f, 0.f};
#pragma unroll
        for (int chunk = 0; chunk < 18; ++chunk) {
            f16x8 a  = *(const f16x8*)&wbf[((og * 18 + chunk) * 64 + lane) * 8];
            f16x8 bb = *(const f16x8*)&sXF[(chunk * 64 + sub * 16 + (pcol ^ sub)) * 8];
            acc = __builtin_amdgcn_mfma_f32_16x16x32_f16(a, bb, acc, 0, 0, 0);
        }
        int row0 = sub * 4;
        ushort* ob = outp + ((size_t)(b * COUT + og * 16 + row0)) * PLANE + rem + pcol;
        ob[0]                 = f2h(acc[0]);
        ob[(size_t)PLANE]     = f2h(acc[1]);
        ob[2 * (size_t)PLANE] = f2h(acc[2]);
        ob[3 * (size_t)PLANE] = f2h(acc[3]);
    }
}

// ---------------- Kernel 3: per-(channel,slice) partial stats, no atomics ---
__global__ __launch_bounds__(256) void kstats(
    const ushort* __restrict__ outp, float* __restrict__ partial)
{
    int o  = blockIdx.x >> 3;
    int sl = blockIdx.x & 7;
    int t  = threadIdx.x;
    float s = 0.f, s2 = 0.f;
    for (int b = 0; b < NB; ++b) {
        const uint4* pl = (const uint4*)(outp + ((size_t)(b * COUT + o)) * PLANE
                                         + sl * (PLANE / 8));
        for (int i = t; i < PLANE / 64; i += 256) {   // 576 uint4 per slice
            uint4 v = pl[i];
            unsigned ua[4] = {v.x, v.y, v.z, v.w};
#pragma unroll
            for (int j = 0; j < 4; ++j) {
                float lo = h2f((ushort)(ua[j] & 0xffff));
                float hi = h2f((ushort)(ua[j] >> 16));
                s  += lo + hi;
                s2 += lo * lo + hi * hi;
            }
        }
    }
    __shared__ float rs[256], rs2[256];
    rs[t] = s; rs2[t] = s2;
    __syncthreads();
    for (int st = 128; st > 0; st >>= 1) {
        if (t < st) { rs[t] += rs[t + st]; rs2[t] += rs2[t + st]; }
        __syncthreads();
    }
    if (t == 0) {
        partial[o * 8 + sl]       = rs[0];
        partial[512 + o * 8 + sl] = rs2[0];
    }
}

// ---------------- Kernel 4: BN finalize + ReLU + 2x2 maxpool ----------------
__global__ __launch_bounds__(256) void kbnpool(
    const ushort* __restrict__ outp, const float* __restrict__ partial,
    const float* __restrict__ gamma, const float* __restrict__ beta,
    float* __restrict__ out)
{
    int i = blockIdx.x * 256 + threadIdx.x;   // 0..2359295 exact
    int wo  = i % 96;
    int tmp = i / 96;
    int ho  = tmp % 96; tmp /= 96;
    int o   = tmp % 64;
    int b   = tmp / 64;
    float s = 0.f, s2 = 0.f;
#pragma unroll
    for (int sl = 0; sl < 8; ++sl) {
        s  += partial[o * 8 + sl];
        s2 += partial[512 + o * 8 + sl];
    }
    float inv  = 1.f / (float)(NB * PLANE);
    float mean = s * inv;
    float var  = s2 * inv - mean * mean;
    float rsq  = rsqrtf(var + 1e-5f);
    float g  = gamma[o] * rsq;
    float bt = beta[o] - mean * g;
    const ushort* pl = outp + ((size_t)(b * COUT + o)) * PLANE + (2 * ho) * HW + 2 * wo;
    unsigned u01 = *(const unsigned*)pl;
    unsigned u23 = *(const unsigned*)(pl + HW);
    float y00 = fmaxf(g * h2f((ushort)(u01 & 0xffff)) + bt, 0.f);
    float y01 = fmaxf(g * h2f((ushort)(u01 >> 16))    + bt, 0.f);
    float y10 = fmaxf(g * h2f((ushort)(u23 & 0xffff)) + bt, 0.f);
    float y11 = fmaxf(g * h2f((ushort)(u23 >> 16))    + bt, 0.f);
    out[i] = fmaxf(fmaxf(y00, y01), fmaxf(y10, y11));
}

// ---------------- launcher --------------------------------------------------
extern "C" void kernel_launch(void* const* d_in, const int* in_sizes, int n_in,
                              void* d_out, int out_size, void* d_ws, size_t ws_size,
                              hipStream_t stream)
{
    const float* x      = (const float*)d_in[0];
    const float* w_p    = (const float*)d_in[1];
    const float* b_p    = (const float*)d_in[2];
    const float* w_m    = (const float*)d_in[3];
    const float* b_m    = (const float*)d_in[4];
    const float* w_conv = (const float*)d_in[5];
    const float* gamma  = (const float*)d_in[6];
    const float* beta   = (const float*)d_in[7];
    float* out = (float*)d_out;

    char* ws = (char*)d_ws;
    ushort* xt      = (ushort*)ws;                    // 19,865,600 B
    ushort* outp    = (ushort*)(ws + 19865600);       // 18,874,368 B
    float*  partial = (float*)(ws + 38739968);        // 4096 B
    ushort* wbf     = (ushort*)(ws + 38744064);       // 73,728 B
    ushort* womf    = (ushort*)(ws + 38817792);       // 36,864 B

    kpadprep<<<NB * H2 + 27, 256, 0, stream>>>(x, w_conv, w_p, w_m, xt, wbf, womf);
    kdeform<<<NBLK, 256, 0, stream>>>(xt, wbf, womf, b_p, b_m, outp);
    kstats<<<512, 256, 0, stream>>>(outp, partial);
    kbnpool<<<(NB * COUT * 96 * 96) / 256, 256, 0, stream>>>(outp, partial, gamma, beta, out);
}